// Round 5
// baseline (363.195 us; speedup 1.0000x reference)
//
#include <hip/hip_runtime.h>

#define HID 64
#define BSHIFT 9            // 512 nodes per bucket
#define NPB 512
#define P3TILE 4096         // edges per block-tile in partition
#define HISTB 512           // hist blocks in fused hist+input kernel
#define PREPB 96            // prep_w blocks fused into hist_input

typedef unsigned int uint;
typedef unsigned short ushort;
typedef unsigned char uchar;
typedef float f32x2 __attribute__((ext_vector_type(2)));
typedef float f32x4 __attribute__((ext_vector_type(4)));
typedef short bf16x8 __attribute__((ext_vector_type(8)));

__device__ inline ushort f2b(float f) {  // fp32 -> bf16 RNE
    uint u = __float_as_uint(f);
    return (ushort)((u + 0x7fffu + ((u >> 16) & 1u)) >> 16);
}

__device__ inline float b2f(ushort b) { return __uint_as_float((uint)b << 16); }

// unpack 16 fp8-e4m3 (uint4) and accumulate into a[8] float2 pairs.
__device__ inline void accf8(f32x2* a, uint4 hv) {
    a[0] += __builtin_bit_cast(f32x2, __builtin_amdgcn_cvt_pk_f32_fp8(hv.x, false));
    a[1] += __builtin_bit_cast(f32x2, __builtin_amdgcn_cvt_pk_f32_fp8(hv.x, true));
    a[2] += __builtin_bit_cast(f32x2, __builtin_amdgcn_cvt_pk_f32_fp8(hv.y, false));
    a[3] += __builtin_bit_cast(f32x2, __builtin_amdgcn_cvt_pk_f32_fp8(hv.y, true));
    a[4] += __builtin_bit_cast(f32x2, __builtin_amdgcn_cvt_pk_f32_fp8(hv.z, false));
    a[5] += __builtin_bit_cast(f32x2, __builtin_amdgcn_cvt_pk_f32_fp8(hv.z, true));
    a[6] += __builtin_bit_cast(f32x2, __builtin_amdgcn_cvt_pk_f32_fp8(hv.w, false));
    a[7] += __builtin_bit_cast(f32x2, __builtin_amdgcn_cvt_pk_f32_fp8(hv.w, true));
}

__device__ inline uchar f2fp8(float f) {
    return (uchar)(__builtin_amdgcn_cvt_pk_fp8_f32(f, f, 0, false) & 0xff);
}

// ------- fused: bucket histogram + input transform + weight prep -------
// h0 fp8 copy stored as two half-feature tables h8a/h8b ([n][32], 3.2MB each)
// so each aggregate phase's gather working set fits a 4MB XCD L2.

__global__ __launch_bounds__(256) void hist_input(const int* __restrict__ dst,
                                                  int* __restrict__ bcnt, int e, int nb,
                                                  const float* __restrict__ x,
                                                  const float* __restrict__ W_in,
                                                  const float* __restrict__ b_in,
                                                  ushort* __restrict__ hb,
                                                  uchar* __restrict__ h8a,
                                                  uchar* __restrict__ h8b, int n,
                                                  int inb,
                                                  const float* __restrict__ Ws,
                                                  const float* __restrict__ Wn,
                                                  ushort* __restrict__ Wcat) {
    __shared__ float smem[576];
    int t = threadIdx.x;
    int b = blockIdx.x;
    if (b < HISTB) {
        int* lh = (int*)smem;
        lh[t] = 0;
        __syncthreads();
        for (int i = b * 256 + t; i < e; i += HISTB * 256)
            atomicAdd(&lh[dst[i] >> BSHIFT], 1);
        __syncthreads();
        if (t < nb && lh[t]) atomicAdd(&bcnt[t], lh[t]);
        return;
    }
    if (b >= HISTB + inb) {   // weight prep range
        int i = (b - HISTB - inb) * 256 + t;
        if (i < 3 * 8192) {
            int l = i >> 13;
            int r = i & 8191;
            int j = r >> 7;
            int k = r & 127;
            float v = (k < 64) ? Ws[l * 4096 + j * 64 + k]
                               : Wn[l * 4096 + j * 64 + (k - 64)];
            Wcat[i] = f2b(v);
        }
        return;
    }
    int ib = b - HISTB;
    float* WlT = smem;          // [8][64]
    float* bl = smem + 512;     // [64]
    for (int i = t; i < 512; i += 256) {
        int j = i >> 3, k = i & 7;
        WlT[k * 64 + j] = W_in[i];
    }
    if (t < 64) bl[t] = b_in[t];
    __syncthreads();
    int total2 = n * 32;
    for (int i = ib * 256 + t; i < total2; i += inb * 256) {
        int v = i >> 5;
        int jp = i & 31;
        int j0 = jp * 2, j1 = jp * 2 + 1;
        const float* xr = x + (size_t)v * 8;
        float s0 = bl[j0], s1 = bl[j1];
#pragma unroll
        for (int k = 0; k < 8; ++k) {
            float xv = xr[k];
            s0 += xv * WlT[k * 64 + j0];
            s1 += xv * WlT[k * 64 + j1];
        }
        float o0 = fmaxf(s0, 0.0f), o1 = fmaxf(s1, 0.0f);
        ((uint*)hb)[i] = (uint)f2b(o0) | ((uint)f2b(o1) << 16);
        int pk = __builtin_amdgcn_cvt_pk_fp8_f32(o0, o1, 0, false);
        uchar* hp = (jp < 16) ? h8a : h8b;
        *(ushort*)&hp[(size_t)v * 32 + (size_t)(jp & 15) * 2] = (ushort)(pk & 0xffff);
    }
}

__global__ void bucket_scan(const int* __restrict__ bcnt, int* __restrict__ bbase,
                            int* __restrict__ bcur, int* __restrict__ offsets,
                            int e, int nb, int n) {
    __shared__ int sd[256];
    int t = threadIdx.x;
    int v = (t < nb) ? bcnt[t] : 0;
    sd[t] = v;
    __syncthreads();
    for (int off = 1; off < 256; off <<= 1) {
        int u = (t >= off) ? sd[t - off] : 0;
        __syncthreads();
        sd[t] += u;
        __syncthreads();
    }
    int excl = t ? sd[t - 1] : 0;
    if (t < nb) { bbase[t] = excl; bcur[t] = excl; }
    if (t == nb) bbase[t] = e;
    if (t == 0) offsets[n] = e;
}

// partition edges into bucket-contiguous packed (src<<9 | dst&511) array.
__global__ __launch_bounds__(256) void partition(const int* __restrict__ src,
                                                 const int* __restrict__ dst,
                                                 int* __restrict__ bcur,
                                                 int* __restrict__ pair, int e, int nb) {
    __shared__ int lh[256], cb[256];
    int t = threadIdx.x;
    int base = blockIdx.x * P3TILE;
    lh[t] = 0;
    __syncthreads();
    int s[16], d[16], r[16];
    if (base + P3TILE <= e) {
        const int4* s4 = (const int4*)(src + base);
        const int4* d4 = (const int4*)(dst + base);
#pragma unroll
        for (int k = 0; k < 4; ++k) {
            int4 sv = s4[t * 4 + k];
            int4 dv = d4[t * 4 + k];
            s[k * 4 + 0] = sv.x; s[k * 4 + 1] = sv.y;
            s[k * 4 + 2] = sv.z; s[k * 4 + 3] = sv.w;
            d[k * 4 + 0] = dv.x; d[k * 4 + 1] = dv.y;
            d[k * 4 + 2] = dv.z; d[k * 4 + 3] = dv.w;
        }
#pragma unroll
        for (int k = 0; k < 16; ++k)
            r[k] = atomicAdd(&lh[d[k] >> BSHIFT], 1);
        __syncthreads();
        if (t < nb && lh[t]) cb[t] = atomicAdd(&bcur[t], lh[t]);
        __syncthreads();
#pragma unroll
        for (int k = 0; k < 16; ++k)
            pair[cb[d[k] >> BSHIFT] + r[k]] = (s[k] << BSHIFT) | (d[k] & (NPB - 1));
    } else {
#pragma unroll
        for (int k = 0; k < 16; ++k) {
            int i = base + t * 16 + k;
            if (i < e) {
                s[k] = src[i];
                d[k] = dst[i];
                r[k] = atomicAdd(&lh[d[k] >> BSHIFT], 1);
            }
        }
        __syncthreads();
        if (t < nb && lh[t]) cb[t] = atomicAdd(&bcur[t], lh[t]);
        __syncthreads();
#pragma unroll
        for (int k = 0; k < 16; ++k) {
            int i = base + t * 16 + k;
            if (i < e)
                pair[cb[d[k] >> BSHIFT] + r[k]] = (s[k] << BSHIFT) | (d[k] & (NPB - 1));
        }
    }
}

// 1024 threads/block: 16 waves for latency hiding
__global__ __launch_bounds__(1024) void build_csr(const int* __restrict__ pair,
                                                  const int* __restrict__ bbase,
                                                  int* __restrict__ offsets,
                                                  float* __restrict__ invdeg,
                                                  int* __restrict__ col, int n) {
    __shared__ int bins[NPB], cur[NPB], sd[NPB];
    int b = blockIdx.x, t = threadIdx.x;
    int cbase = bbase[b], cend = bbase[b + 1];
    int v0 = b << BSHIFT;
    if (t < NPB) bins[t] = 0;
    __syncthreads();
    for (int i = cbase + t; i < cend; i += 1024)
        atomicAdd(&bins[pair[i] & (NPB - 1)], 1);
    __syncthreads();
    int d = (t < NPB) ? bins[t] : 0;
    if (t < NPB) sd[t] = d;
    __syncthreads();
    for (int off = 1; off < NPB; off <<= 1) {
        int u = (t < NPB && t >= off) ? sd[t - off] : 0;
        __syncthreads();
        if (t < NPB) sd[t] += u;
        __syncthreads();
    }
    if (t < NPB) {
        int excl = sd[t] - d;
        cur[t] = excl;
        int v = v0 + t;
        if (v < n) {
            offsets[v] = cbase + excl;
            invdeg[v] = d > 0 ? 1.0f / (float)d : 0.0f;
        }
    }
    __syncthreads();
    for (int i = cbase + t; i < cend; i += 1024) {
        int p = pair[i];
        int pos = atomicAdd(&cur[p & (NPB - 1)], 1);
        col[cbase + pos] = p >> BSHIFT;
    }
}

// ---- neighbor mean, one 32-feature half per phase (table L2-resident) ----
// Lane map per quarter (16 lanes / node): e2 = lane&1 selects which 16B of the
// 32B half-row, sl = (lane>>1)&7 is the edge slot (8 edges in flight/quarter).
// Phases write disjoint halves of nmb -> no partial round-trip.

template <int PHASE>
__global__ __launch_bounds__(256) void aggregate_half(const uchar* __restrict__ tab,
                                                      ushort* __restrict__ nmb,
                                                      const int* __restrict__ offsets,
                                                      const int* __restrict__ col,
                                                      const float* __restrict__ invdeg,
                                                      int n) {
    int t = threadIdx.x, lane = t & 63, wid = t >> 6;
    int q = lane >> 4;          // quarter -> node
    int fl = lane & 15;         // col staging lane
    int e2 = lane & 1;          // which 16B (16 features) of the 32B half-row
    int sl = (lane >> 1) & 7;   // edge slot
    int nwaves = gridDim.x * 4;
    int ngrp = (n + 3) >> 2;
    for (int w = blockIdx.x * 4 + wid; w < ngrp; w += nwaves) {
        int v = w * 4 + q;
        bool valid = v < n;
        int vv = valid ? v : n - 1;
        int o0 = offsets[vv], o1 = offsets[vv + 1];
        int deg = o1 - o0;
        const int* cp = col + o0;
        int deg16 = deg & ~15;
        f32x2 acc2[8];
        float* af = (float*)acc2;
#pragma unroll
        for (int k = 0; k < 8; ++k) acc2[k] = f32x2{0.f, 0.f};
        for (int base = 0; base < deg16; base += 16) {
            int idx16 = cp[base + fl];  // full chunk: unguarded, coalesced
#pragma unroll
            for (int jj = 0; jj < 16; jj += 8) {
                int ne = __shfl(idx16, q * 16 + jj + sl);
                uint4 hv = *(const uint4*)&tab[(size_t)ne * 32 + e2 * 16];
                accf8(acc2, hv);
            }
        }
        // tail (<16 edges): guarded, direct quarter-local col loads
        for (int jj = 0; jj < 16; jj += 8) {
            if (deg16 + jj >= deg) break;   // uniform within quarter
            int j = deg16 + jj + sl;
            if (j < deg) {
                int ne = cp[j];
                uint4 hv = *(const uint4*)&tab[(size_t)ne * 32 + e2 * 16];
                accf8(acc2, hv);
            }
        }
        // reduce over the 8 edge slots (lane bits 1-3)
#pragma unroll
        for (int k = 0; k < 16; ++k) {
            af[k] += __shfl_xor(af[k], 2);
            af[k] += __shfl_xor(af[k], 4);
            af[k] += __shfl_xor(af[k], 8);
        }
        if (valid && sl == 0) {
            float s = invdeg[vv];
            uint4 lo, hi;
            lo.x = (uint)f2b(af[0] * s) | ((uint)f2b(af[1] * s) << 16);
            lo.y = (uint)f2b(af[2] * s) | ((uint)f2b(af[3] * s) << 16);
            lo.z = (uint)f2b(af[4] * s) | ((uint)f2b(af[5] * s) << 16);
            lo.w = (uint)f2b(af[6] * s) | ((uint)f2b(af[7] * s) << 16);
            hi.x = (uint)f2b(af[8] * s) | ((uint)f2b(af[9] * s) << 16);
            hi.y = (uint)f2b(af[10] * s) | ((uint)f2b(af[11] * s) << 16);
            hi.z = (uint)f2b(af[12] * s) | ((uint)f2b(af[13] * s) << 16);
            hi.w = (uint)f2b(af[14] * s) | ((uint)f2b(af[15] * s) << 16);
            ushort* dst = nmb + (size_t)v * HID + PHASE * 32 + e2 * 16;
            *(uint4*)dst = lo;
            *(uint4*)(dst + 8) = hi;
        }
    }
}

// ---------------- per-layer transform via MFMA, bf16 residual ----------------

__global__ __launch_bounds__(256) void transform_mfma(
    const ushort* __restrict__ hbm, const ushort* __restrict__ nmb,
    ushort* __restrict__ hbout, uchar* __restrict__ h8a,
    uchar* __restrict__ h8b,
    float* __restrict__ outF, const ushort* __restrict__ Wcat,
    const float* __restrict__ bias, const float* __restrict__ gamma,
    const float* __restrict__ beta, int n, int last) {
    int t = threadIdx.x, lane = t & 63, wid = t >> 6;
    int c = lane & 15, g = lane >> 4;
    bf16x8 Bf[4][4];
#pragma unroll
    for (int tt = 0; tt < 4; ++tt)
#pragma unroll
        for (int s = 0; s < 4; ++s)
            Bf[s][tt] = *(const bf16x8*)&Wcat[(tt * 16 + c) * 128 + s * 32 + g * 8];
    float bcol[4], gcol[4], btc[4];
#pragma unroll
    for (int tt = 0; tt < 4; ++tt) {
        bcol[tt] = bias[tt * 16 + c];
        gcol[tt] = gamma[tt * 16 + c];
        btc[tt] = beta[tt * 16 + c];
    }
    int ntiles = (n + 15) >> 4;
    int nw = gridDim.x * 4;
    for (int tile = blockIdx.x * 4 + wid; tile < ntiles; tile += nw) {
        int m0 = tile << 4;
        int node = m0 + c;
        int nodeL = node < n ? node : n - 1;
        bf16x8 Af[4];
#pragma unroll
        for (int s = 0; s < 2; ++s)
            Af[s] = *(const bf16x8*)&hbm[(size_t)nodeL * HID + s * 32 + g * 8];
#pragma unroll
        for (int s = 0; s < 2; ++s)
            Af[2 + s] = *(const bf16x8*)&nmb[(size_t)nodeL * HID + s * 32 + g * 8];
        f32x4 acc[4] = {{0, 0, 0, 0}, {0, 0, 0, 0}, {0, 0, 0, 0}, {0, 0, 0, 0}};
#pragma unroll
        for (int tt = 0; tt < 4; ++tt)
#pragma unroll
            for (int s = 0; s < 4; ++s)
                acc[tt] = __builtin_amdgcn_mfma_f32_16x16x32_bf16(Af[s], Bf[s][tt],
                                                                 acc[tt], 0, 0, 0);
        float v[4][4];
#pragma unroll
        for (int tt = 0; tt < 4; ++tt)
#pragma unroll
            for (int r = 0; r < 4; ++r) v[tt][r] = acc[tt][r] + bcol[tt];
#pragma unroll
        for (int r = 0; r < 4; ++r) {
            float s = v[0][r] + v[1][r] + v[2][r] + v[3][r];
            s += __shfl_xor(s, 1);
            s += __shfl_xor(s, 2);
            s += __shfl_xor(s, 4);
            s += __shfl_xor(s, 8);
            float mu = s * (1.0f / 64.0f);
            float ss = 0.f;
#pragma unroll
            for (int tt = 0; tt < 4; ++tt) {
                float d = v[tt][r] - mu;
                ss += d * d;
            }
            ss += __shfl_xor(ss, 1);
            ss += __shfl_xor(ss, 2);
            ss += __shfl_xor(ss, 4);
            ss += __shfl_xor(ss, 8);
            float inv = rsqrtf(ss * (1.0f / 64.0f) + 1e-5f);
            int nr = m0 + g * 4 + r;
            if (nr < n) {
#pragma unroll
                for (int tt = 0; tt < 4; ++tt) {
                    int j = tt * 16 + c;
                    float hl = (v[tt][r] - mu) * inv * gcol[tt] + btc[tt];
                    float hv = b2f(hbm[(size_t)nr * HID + j]);
                    float o = hv + fmaxf(hl, 0.0f);
                    if (last) {
                        outF[(size_t)nr * HID + j] = o;   // hb/h8 writes dead
                    } else {
                        hbout[(size_t)nr * HID + j] = f2b(o);
                        uchar* hp = (tt < 2) ? h8a : h8b;
                        hp[(size_t)nr * 32 + (tt & 1) * 16 + c] = f2fp8(o);
                    }
                }
            }
        }
    }
}

// ---------------- launcher ----------------

extern "C" void kernel_launch(void* const* d_in, const int* in_sizes, int n_in,
                              void* d_out, int out_size, void* d_ws, size_t ws_size,
                              hipStream_t stream) {
    const float* x = (const float*)d_in[0];
    const int* edge_src = (const int*)d_in[1];
    const int* edge_dst = (const int*)d_in[2];
    const float* W_in = (const float*)d_in[3];
    const float* b_in = (const float*)d_in[4];
    const float* Ws_self = (const float*)d_in[5];
    const float* Ws_neigh = (const float*)d_in[6];
    const float* biases = (const float*)d_in[7];
    const float* gammas = (const float*)d_in[8];
    const float* betas = (const float*)d_in[9];
    float* out = (float*)d_out;

    int n = in_sizes[0] / 8;
    int e = in_sizes[1];
    int nb = (n + NPB - 1) >> BSHIFT;

    char* w = (char*)d_ws;
    size_t off = 0;
    auto carve = [&](size_t bytes) -> void* {
        void* p = w + off;
        off = (off + bytes + 255) & ~(size_t)255;
        return p;
    };
    int* offsets = (int*)carve((size_t)(n + 1) * 4);
    float* invdeg = (float*)carve((size_t)n * 4);
    int* bcnt = (int*)carve(1024 * 4);
    int* bbase = (int*)carve(1024 * 4);
    int* bcur = (int*)carve(1024 * 4);
    int* col = (int*)carve((size_t)e * 4);
    int* pairbuf = (int*)carve((size_t)e * 4);
    ushort* hb = (ushort*)carve((size_t)n * HID * 2);
    ushort* nm16 = (ushort*)carve((size_t)n * HID * 2);
    uchar* h8a = (uchar*)carve((size_t)n * 32);
    uchar* h8b = (uchar*)carve((size_t)n * 32);
    ushort* Wcat = (ushort*)carve(3 * 64 * 128 * 2);
    (void)ws_size;

    hipMemsetAsync(bcnt, 0, 1024 * 4, stream);
    hist_input<<<HISTB + 2048 + PREPB, 256, 0, stream>>>(edge_dst, bcnt, e, nb,
                                                         x, W_in, b_in, hb, h8a, h8b, n,
                                                         2048, Ws_self, Ws_neigh, Wcat);
    bucket_scan<<<1, 256, 0, stream>>>(bcnt, bbase, bcur, offsets, e, nb, n);
    partition<<<(e + P3TILE - 1) / P3TILE, 256, 0, stream>>>(edge_src, edge_dst, bcur,
                                                            pairbuf, e, nb);
    build_csr<<<nb, 1024, 0, stream>>>(pairbuf, bbase, offsets, invdeg, col, n);

    int tfblocks = ((n + 15) / 16 + 3) / 4;
    for (int l = 0; l < 3; ++l) {
        aggregate_half<0><<<2048, 256, 0, stream>>>(h8a, nm16, offsets, col, invdeg, n);
        aggregate_half<1><<<2048, 256, 0, stream>>>(h8b, nm16, offsets, col, invdeg, n);
        transform_mfma<<<tfblocks, 256, 0, stream>>>(hb, nm16, hb, h8a, h8b, out,
                                                     Wcat + (size_t)l * 8192,
                                                     biases + l * 64, gammas + l * 64,
                                                     betas + l * 64, n, l == 2 ? 1 : 0);
    }
}

// Round 6
// 288.967 us; speedup vs baseline: 1.2569x; 1.2569x over previous
//
#include <hip/hip_runtime.h>

#define HID 64
#define BSHIFT 9            // 512 nodes per bucket
#define NPB 512
#define P3TILE 4096         // edges per block-tile in partition
#define HISTB 512           // hist blocks in fused hist+input kernel
#define PREPB 96            // prep_w blocks fused into hist_input

typedef unsigned int uint;
typedef unsigned short ushort;
typedef unsigned char uchar;
typedef float f32x2 __attribute__((ext_vector_type(2)));
typedef float f32x4 __attribute__((ext_vector_type(4)));
typedef short bf16x8 __attribute__((ext_vector_type(8)));

__device__ inline ushort f2b(float f) {  // fp32 -> bf16 RNE
    uint u = __float_as_uint(f);
    return (ushort)((u + 0x7fffu + ((u >> 16) & 1u)) >> 16);
}

__device__ inline float b2f(ushort b) { return __uint_as_float((uint)b << 16); }

// unpack 16 fp8-e4m3 (uint4) and accumulate into a[8] float2 pairs.
__device__ inline void accf8(f32x2* a, uint4 hv) {
    a[0] += __builtin_bit_cast(f32x2, __builtin_amdgcn_cvt_pk_f32_fp8(hv.x, false));
    a[1] += __builtin_bit_cast(f32x2, __builtin_amdgcn_cvt_pk_f32_fp8(hv.x, true));
    a[2] += __builtin_bit_cast(f32x2, __builtin_amdgcn_cvt_pk_f32_fp8(hv.y, false));
    a[3] += __builtin_bit_cast(f32x2, __builtin_amdgcn_cvt_pk_f32_fp8(hv.y, true));
    a[4] += __builtin_bit_cast(f32x2, __builtin_amdgcn_cvt_pk_f32_fp8(hv.z, false));
    a[5] += __builtin_bit_cast(f32x2, __builtin_amdgcn_cvt_pk_f32_fp8(hv.z, true));
    a[6] += __builtin_bit_cast(f32x2, __builtin_amdgcn_cvt_pk_f32_fp8(hv.w, false));
    a[7] += __builtin_bit_cast(f32x2, __builtin_amdgcn_cvt_pk_f32_fp8(hv.w, true));
}

__device__ inline uchar f2fp8(float f) {
    return (uchar)(__builtin_amdgcn_cvt_pk_fp8_f32(f, f, 0, false) & 0xff);
}

// ------- fused: bucket histogram + input transform + weight prep -------

__global__ __launch_bounds__(256) void hist_input(const int* __restrict__ dst,
                                                  int* __restrict__ bcnt, int e, int nb,
                                                  const float* __restrict__ x,
                                                  const float* __restrict__ W_in,
                                                  const float* __restrict__ b_in,
                                                  ushort* __restrict__ hb,
                                                  uchar* __restrict__ h8, int n,
                                                  int inb,
                                                  const float* __restrict__ Ws,
                                                  const float* __restrict__ Wn,
                                                  ushort* __restrict__ Wcat) {
    __shared__ float smem[576];
    int t = threadIdx.x;
    int b = blockIdx.x;
    if (b < HISTB) {
        int* lh = (int*)smem;
        lh[t] = 0;
        __syncthreads();
        for (int i = b * 256 + t; i < e; i += HISTB * 256)
            atomicAdd(&lh[dst[i] >> BSHIFT], 1);
        __syncthreads();
        if (t < nb && lh[t]) atomicAdd(&bcnt[t], lh[t]);
        return;
    }
    if (b >= HISTB + inb) {   // weight prep range
        int i = (b - HISTB - inb) * 256 + t;
        if (i < 3 * 8192) {
            int l = i >> 13;
            int r = i & 8191;
            int j = r >> 7;
            int k = r & 127;
            float v = (k < 64) ? Ws[l * 4096 + j * 64 + k]
                               : Wn[l * 4096 + j * 64 + (k - 64)];
            Wcat[i] = f2b(v);
        }
        return;
    }
    int ib = b - HISTB;
    float* WlT = smem;          // [8][64]
    float* bl = smem + 512;     // [64]
    for (int i = t; i < 512; i += 256) {
        int j = i >> 3, k = i & 7;
        WlT[k * 64 + j] = W_in[i];
    }
    if (t < 64) bl[t] = b_in[t];
    __syncthreads();
    int total2 = n * 32;
    for (int i = ib * 256 + t; i < total2; i += inb * 256) {
        int v = i >> 5;
        int jp = i & 31;
        int j0 = jp * 2, j1 = jp * 2 + 1;
        const float* xr = x + (size_t)v * 8;
        float s0 = bl[j0], s1 = bl[j1];
#pragma unroll
        for (int k = 0; k < 8; ++k) {
            float xv = xr[k];
            s0 += xv * WlT[k * 64 + j0];
            s1 += xv * WlT[k * 64 + j1];
        }
        float o0 = fmaxf(s0, 0.0f), o1 = fmaxf(s1, 0.0f);
        ((uint*)hb)[i] = (uint)f2b(o0) | ((uint)f2b(o1) << 16);
        int pk = __builtin_amdgcn_cvt_pk_fp8_f32(o0, o1, 0, false);
        *(ushort*)&h8[(size_t)2 * i] = (ushort)(pk & 0xffff);
    }
}

__global__ void bucket_scan(const int* __restrict__ bcnt, int* __restrict__ bbase,
                            int* __restrict__ bcur, int* __restrict__ offsets,
                            int e, int nb, int n) {
    __shared__ int sd[256];
    int t = threadIdx.x;
    int v = (t < nb) ? bcnt[t] : 0;
    sd[t] = v;
    __syncthreads();
    for (int off = 1; off < 256; off <<= 1) {
        int u = (t >= off) ? sd[t - off] : 0;
        __syncthreads();
        sd[t] += u;
        __syncthreads();
    }
    int excl = t ? sd[t - 1] : 0;
    if (t < nb) { bbase[t] = excl; bcur[t] = excl; }
    if (t == nb) bbase[t] = e;
    if (t == 0) offsets[n] = e;
}

// partition edges into bucket-contiguous packed (src<<9 | dst&511) array.
__global__ __launch_bounds__(256) void partition(const int* __restrict__ src,
                                                 const int* __restrict__ dst,
                                                 int* __restrict__ bcur,
                                                 int* __restrict__ pair, int e, int nb) {
    __shared__ int lh[256], cb[256];
    int t = threadIdx.x;
    int base = blockIdx.x * P3TILE;
    lh[t] = 0;
    __syncthreads();
    int s[16], d[16], r[16];
    if (base + P3TILE <= e) {
        const int4* s4 = (const int4*)(src + base);
        const int4* d4 = (const int4*)(dst + base);
#pragma unroll
        for (int k = 0; k < 4; ++k) {
            int4 sv = s4[t * 4 + k];
            int4 dv = d4[t * 4 + k];
            s[k * 4 + 0] = sv.x; s[k * 4 + 1] = sv.y;
            s[k * 4 + 2] = sv.z; s[k * 4 + 3] = sv.w;
            d[k * 4 + 0] = dv.x; d[k * 4 + 1] = dv.y;
            d[k * 4 + 2] = dv.z; d[k * 4 + 3] = dv.w;
        }
#pragma unroll
        for (int k = 0; k < 16; ++k)
            r[k] = atomicAdd(&lh[d[k] >> BSHIFT], 1);
        __syncthreads();
        if (t < nb && lh[t]) cb[t] = atomicAdd(&bcur[t], lh[t]);
        __syncthreads();
#pragma unroll
        for (int k = 0; k < 16; ++k)
            pair[cb[d[k] >> BSHIFT] + r[k]] = (s[k] << BSHIFT) | (d[k] & (NPB - 1));
    } else {
#pragma unroll
        for (int k = 0; k < 16; ++k) {
            int i = base + t * 16 + k;
            if (i < e) {
                s[k] = src[i];
                d[k] = dst[i];
                r[k] = atomicAdd(&lh[d[k] >> BSHIFT], 1);
            }
        }
        __syncthreads();
        if (t < nb && lh[t]) cb[t] = atomicAdd(&bcur[t], lh[t]);
        __syncthreads();
#pragma unroll
        for (int k = 0; k < 16; ++k) {
            int i = base + t * 16 + k;
            if (i < e)
                pair[cb[d[k] >> BSHIFT] + r[k]] = (s[k] << BSHIFT) | (d[k] & (NPB - 1));
        }
    }
}

// 1024 threads/block: 16 waves for latency hiding
__global__ __launch_bounds__(1024) void build_csr(const int* __restrict__ pair,
                                                  const int* __restrict__ bbase,
                                                  int* __restrict__ offsets,
                                                  float* __restrict__ invdeg,
                                                  int* __restrict__ col, int n) {
    __shared__ int bins[NPB], cur[NPB], sd[NPB];
    int b = blockIdx.x, t = threadIdx.x;
    int cbase = bbase[b], cend = bbase[b + 1];
    int v0 = b << BSHIFT;
    if (t < NPB) bins[t] = 0;
    __syncthreads();
    for (int i = cbase + t; i < cend; i += 1024)
        atomicAdd(&bins[pair[i] & (NPB - 1)], 1);
    __syncthreads();
    int d = (t < NPB) ? bins[t] : 0;
    if (t < NPB) sd[t] = d;
    __syncthreads();
    for (int off = 1; off < NPB; off <<= 1) {
        int u = (t < NPB && t >= off) ? sd[t - off] : 0;
        __syncthreads();
        if (t < NPB) sd[t] += u;
        __syncthreads();
    }
    if (t < NPB) {
        int excl = sd[t] - d;
        cur[t] = excl;
        int v = v0 + t;
        if (v < n) {
            offsets[v] = cbase + excl;
            invdeg[v] = d > 0 ? 1.0f / (float)d : 0.0f;
        }
    }
    __syncthreads();
    for (int i = cbase + t; i < cend; i += 1024) {
        int p = pair[i];
        int pos = atomicAdd(&cur[p & (NPB - 1)], 1);
        col[cbase + pos] = p >> BSHIFT;
    }
}

// -------- fused aggregate + transform: one wave owns a 16-node tile --------
// 4 aggregate passes (4 nodes each, same inner loop as the 303.7µs kernel)
// deposit bf16 neighbor means into a wave-private LDS slab; then the wave
// loads its MFMA fragments from LDS and runs the transform. No nm16
// round-trip, no extra launch, and gather stalls of some waves overlap with
// MFMA/LN compute of others. h8 is double-buffered (hin != hout) because
// finished tiles write next-layer h8 while others still gather this layer's.

template <int LAST>
__global__ __launch_bounds__(256) void agg_tf(
    const uchar* __restrict__ h8in, const ushort* __restrict__ hbm,
    ushort* __restrict__ hbout, uchar* __restrict__ h8out,
    float* __restrict__ outF,
    const int* __restrict__ offsets, const int* __restrict__ col,
    const float* __restrict__ invdeg,
    const ushort* __restrict__ Wcat, const float* __restrict__ bias,
    const float* __restrict__ gamma, const float* __restrict__ beta, int n) {
    __shared__ ushort nmlds[4][16][72];   // 72: pad so frag reads are 2-way max
    int t = threadIdx.x, lane = t & 63, wid = t >> 6;
    int ntiles = (n + 15) >> 4;
    int tile = blockIdx.x * 4 + wid;
    if (tile >= ntiles) return;
    int m0 = tile << 4;
    int q = lane >> 4;          // quarter -> node within pass
    int fl = lane & 15;         // col staging lane
    int e4 = lane & 3;          // which 16B of the 64B row
    int sl = (lane >> 2) & 3;   // edge slot
    // ---- aggregate 16 nodes in 4 passes of 4 ----
    for (int p = 0; p < 4; ++p) {
        int v = m0 + p * 4 + q;
        int vv = v < n ? v : n - 1;
        int o0 = offsets[vv], o1 = offsets[vv + 1];
        int deg = o1 - o0;
        const int* cp = col + o0;
        int deg16 = deg & ~15;
        f32x2 acc2[8];
        float* af = (float*)acc2;
#pragma unroll
        for (int k = 0; k < 8; ++k) acc2[k] = f32x2{0.f, 0.f};
        for (int base = 0; base < deg16; base += 16) {
            int idx16 = cp[base + fl];
#pragma unroll
            for (int jj = 0; jj < 16; jj += 4) {
                int ne = __shfl(idx16, q * 16 + jj + sl);
                uint4 hv = *(const uint4*)&h8in[(size_t)ne * HID + e4 * 16];
                accf8(acc2, hv);
            }
        }
        for (int jj = 0; jj < 16; jj += 4) {
            if (deg16 + jj >= deg) break;   // uniform within quarter
            int j = deg16 + jj + sl;
            if (j < deg) {
                int ne = cp[j];
                uint4 hv = *(const uint4*)&h8in[(size_t)ne * HID + e4 * 16];
                accf8(acc2, hv);
            }
        }
#pragma unroll
        for (int k = 0; k < 16; ++k) {
            af[k] += __shfl_xor(af[k], 4);
            af[k] += __shfl_xor(af[k], 8);
        }
        if (sl == 0) {
            float s = invdeg[vv];
            uint4 lo, hi;
            lo.x = (uint)f2b(af[0] * s) | ((uint)f2b(af[1] * s) << 16);
            lo.y = (uint)f2b(af[2] * s) | ((uint)f2b(af[3] * s) << 16);
            lo.z = (uint)f2b(af[4] * s) | ((uint)f2b(af[5] * s) << 16);
            lo.w = (uint)f2b(af[6] * s) | ((uint)f2b(af[7] * s) << 16);
            hi.x = (uint)f2b(af[8] * s) | ((uint)f2b(af[9] * s) << 16);
            hi.y = (uint)f2b(af[10] * s) | ((uint)f2b(af[11] * s) << 16);
            hi.z = (uint)f2b(af[12] * s) | ((uint)f2b(af[13] * s) << 16);
            hi.w = (uint)f2b(af[14] * s) | ((uint)f2b(af[15] * s) << 16);
            *(uint4*)&nmlds[wid][p * 4 + q][e4 * 16] = lo;
            *(uint4*)&nmlds[wid][p * 4 + q][e4 * 16 + 8] = hi;
        }
    }
    // LDS slab is wave-private: no barrier needed (lgkmcnt ordering only).
    // ---- transform (identical math to round-3 transform_mfma) ----
    int c = lane & 15, g = lane >> 4;
    bf16x8 Bf[4][4];
#pragma unroll
    for (int tt = 0; tt < 4; ++tt)
#pragma unroll
        for (int s = 0; s < 4; ++s)
            Bf[s][tt] = *(const bf16x8*)&Wcat[(tt * 16 + c) * 128 + s * 32 + g * 8];
    float bcol[4], gcol[4], btc[4];
#pragma unroll
    for (int tt = 0; tt < 4; ++tt) {
        bcol[tt] = bias[tt * 16 + c];
        gcol[tt] = gamma[tt * 16 + c];
        btc[tt] = beta[tt * 16 + c];
    }
    int node = m0 + c;
    int nodeL = node < n ? node : n - 1;
    bf16x8 Af[4];
#pragma unroll
    for (int s = 0; s < 2; ++s)
        Af[s] = *(const bf16x8*)&hbm[(size_t)nodeL * HID + s * 32 + g * 8];
#pragma unroll
    for (int s = 0; s < 2; ++s)
        Af[2 + s] = *(const bf16x8*)&nmlds[wid][c][s * 32 + g * 8];
    f32x4 acc[4] = {{0, 0, 0, 0}, {0, 0, 0, 0}, {0, 0, 0, 0}, {0, 0, 0, 0}};
#pragma unroll
    for (int tt = 0; tt < 4; ++tt)
#pragma unroll
        for (int s = 0; s < 4; ++s)
            acc[tt] = __builtin_amdgcn_mfma_f32_16x16x32_bf16(Af[s], Bf[s][tt],
                                                             acc[tt], 0, 0, 0);
    float v[4][4];
#pragma unroll
    for (int tt = 0; tt < 4; ++tt)
#pragma unroll
        for (int r = 0; r < 4; ++r) v[tt][r] = acc[tt][r] + bcol[tt];
#pragma unroll
    for (int r = 0; r < 4; ++r) {
        float s = v[0][r] + v[1][r] + v[2][r] + v[3][r];
        s += __shfl_xor(s, 1);
        s += __shfl_xor(s, 2);
        s += __shfl_xor(s, 4);
        s += __shfl_xor(s, 8);
        float mu = s * (1.0f / 64.0f);
        float ss = 0.f;
#pragma unroll
        for (int tt = 0; tt < 4; ++tt) {
            float d = v[tt][r] - mu;
            ss += d * d;
        }
        ss += __shfl_xor(ss, 1);
        ss += __shfl_xor(ss, 2);
        ss += __shfl_xor(ss, 4);
        ss += __shfl_xor(ss, 8);
        float inv = rsqrtf(ss * (1.0f / 64.0f) + 1e-5f);
        int nr = m0 + g * 4 + r;
        if (nr < n) {
#pragma unroll
            for (int tt = 0; tt < 4; ++tt) {
                int j = tt * 16 + c;
                float hl = (v[tt][r] - mu) * inv * gcol[tt] + btc[tt];
                float hv = b2f(hbm[(size_t)nr * HID + j]);
                float o = hv + fmaxf(hl, 0.0f);
                if (LAST) {
                    outF[(size_t)nr * HID + j] = o;
                } else {
                    hbout[(size_t)nr * HID + j] = f2b(o);
                    h8out[(size_t)nr * HID + j] = f2fp8(o);
                }
            }
        }
    }
}

// ---------------- launcher ----------------

extern "C" void kernel_launch(void* const* d_in, const int* in_sizes, int n_in,
                              void* d_out, int out_size, void* d_ws, size_t ws_size,
                              hipStream_t stream) {
    const float* x = (const float*)d_in[0];
    const int* edge_src = (const int*)d_in[1];
    const int* edge_dst = (const int*)d_in[2];
    const float* W_in = (const float*)d_in[3];
    const float* b_in = (const float*)d_in[4];
    const float* Ws_self = (const float*)d_in[5];
    const float* Ws_neigh = (const float*)d_in[6];
    const float* biases = (const float*)d_in[7];
    const float* gammas = (const float*)d_in[8];
    const float* betas = (const float*)d_in[9];
    float* out = (float*)d_out;

    int n = in_sizes[0] / 8;
    int e = in_sizes[1];
    int nb = (n + NPB - 1) >> BSHIFT;

    char* w = (char*)d_ws;
    size_t off = 0;
    auto carve = [&](size_t bytes) -> void* {
        void* p = w + off;
        off = (off + bytes + 255) & ~(size_t)255;
        return p;
    };
    int* offsets = (int*)carve((size_t)(n + 1) * 4);
    float* invdeg = (float*)carve((size_t)n * 4);
    int* bcnt = (int*)carve(1024 * 4);
    int* bbase = (int*)carve(1024 * 4);
    int* bcur = (int*)carve(1024 * 4);
    int* col = (int*)carve((size_t)e * 4);
    int* pairbuf = (int*)carve((size_t)e * 4);
    ushort* hb = (ushort*)carve((size_t)n * HID * 2);
    uchar* h8A = (uchar*)carve((size_t)n * HID);
    uchar* h8B = (uchar*)carve((size_t)n * HID);
    ushort* Wcat = (ushort*)carve(3 * 64 * 128 * 2);
    (void)ws_size;

    hipMemsetAsync(bcnt, 0, 1024 * 4, stream);
    hist_input<<<HISTB + 2048 + PREPB, 256, 0, stream>>>(edge_dst, bcnt, e, nb,
                                                         x, W_in, b_in, hb, h8A, n,
                                                         2048, Ws_self, Ws_neigh, Wcat);
    bucket_scan<<<1, 256, 0, stream>>>(bcnt, bbase, bcur, offsets, e, nb, n);
    partition<<<(e + P3TILE - 1) / P3TILE, 256, 0, stream>>>(edge_src, edge_dst, bcur,
                                                            pairbuf, e, nb);
    build_csr<<<nb, 1024, 0, stream>>>(pairbuf, bbase, offsets, invdeg, col, n);

    int ntiles = (n + 15) >> 4;
    int ablocks = (ntiles + 3) / 4;    // one 16-node tile per wave
    uchar* hin = h8A;
    uchar* hout = h8B;
    for (int l = 0; l < 3; ++l) {
        if (l < 2) {
            agg_tf<0><<<ablocks, 256, 0, stream>>>(hin, hb, hb, hout, out,
                                                   offsets, col, invdeg,
                                                   Wcat + (size_t)l * 8192,
                                                   biases + l * 64, gammas + l * 64,
                                                   betas + l * 64, n);
        } else {
            agg_tf<1><<<ablocks, 256, 0, stream>>>(hin, hb, hb, hout, out,
                                                   offsets, col, invdeg,
                                                   Wcat + (size_t)l * 8192,
                                                   biases + l * 64, gammas + l * 64,
                                                   betas + l * 64, n);
        }
        uchar* tmp = hin; hin = hout; hout = tmp;
    }
}